// Round 1
// baseline (138.897 us; speedup 1.0000x reference)
//
#include <hip/hip_runtime.h>
#include <stdint.h>

// Problem constants (fixed shapes from reference)
#define M_ROWS 6272   // 32*196
#define K_DIM  768
#define N_DIM  3072
#define BM 128
#define BN 128
#define BK 32

typedef unsigned short u16;
typedef __attribute__((ext_vector_type(8))) __bf16 bf16x8;
typedef __attribute__((ext_vector_type(4))) float f32x4;

__device__ __forceinline__ u16 f32_to_bf16(float f) {
    unsigned u = __float_as_uint(f);
    unsigned r = 0x7FFFu + ((u >> 16) & 1u);
    return (u16)((u + r) >> 16);
}

__device__ __forceinline__ unsigned pack2(float a, float b) {
    return (unsigned)f32_to_bf16(a) | ((unsigned)f32_to_bf16(b) << 16);
}

// x fp32 [6272,768] -> bf16, 8 elements/thread, 602112 chunks
__global__ void cast_x_kernel(const float* __restrict__ x, u16* __restrict__ xb) {
    int idx = blockIdx.x * 256 + threadIdx.x;
    const float4* xp = (const float4*)x + (size_t)idx * 2;
    float4 a = xp[0], b = xp[1];
    uint4 v;
    v.x = pack2(a.x, a.y);
    v.y = pack2(a.z, a.w);
    v.z = pack2(b.x, b.y);
    v.w = pack2(b.z, b.w);
    ((uint4*)xb)[idx] = v;
}

// Expand block-circulant weight into Wbig bf16 [3072,768]:
// Wbig[kblk*768+o][j*192+c] = W[(kblk-j)%4][o][c].  8 elements/thread, 294912 chunks.
__global__ void expand_w_kernel(const float* __restrict__ w, u16* __restrict__ wb) {
    int idx = blockIdx.x * 256 + threadIdx.x;
    int n    = idx / 96;          // output row [0,3072)
    int kc   = idx - n * 96;      // 8-elem chunk along K
    int kblk = n / 768;           // 0..3
    int o    = n - kblk * 768;    // 0..767
    int j    = kc / 24;           // 0..3  (k = kc*8, 192/8=24 chunks per j-block)
    int c8   = kc - j * 24;       // 0..23
    int i    = (kblk - j) & 3;    // (kblk - j) mod 4 (& works for negatives)
    const float* src = w + (((size_t)i * 768 + o) * 192 + c8 * 8);
    float4 a = ((const float4*)src)[0];
    float4 b = ((const float4*)src)[1];
    uint4 v;
    v.x = pack2(a.x, a.y);
    v.y = pack2(a.z, a.w);
    v.z = pack2(b.x, b.y);
    v.w = pack2(b.z, b.w);
    ((uint4*)wb)[idx] = v;
}

__device__ __forceinline__ void load_lds16(const u16* g, u16* l) {
    __builtin_amdgcn_global_load_lds(
        (const __attribute__((address_space(1))) void*)g,
        (__attribute__((address_space(3))) void*)l, 16, 0, 0);
}

// C[m,n] = sum_k A[m,k]*B[n,k] + bias[n]; A,B bf16 row-major K-contig, C fp32.
__global__ __launch_bounds__(256) void gemm_bt(
    const u16* __restrict__ A,    // [M_ROWS, K_DIM] bf16
    const u16* __restrict__ B,    // [N_DIM,  K_DIM] bf16
    const float* __restrict__ bias,
    float* __restrict__ C)
{
    __shared__ u16 As[BM * BK];   // 8 KB
    __shared__ u16 Bs[BN * BK];   // 8 KB

    const int tid    = threadIdx.x;
    const int wave   = tid >> 6;
    const int lane   = tid & 63;
    const int lane16 = lane & 15;
    const int quad   = lane >> 4;
    const int wr     = wave >> 1;   // wave row (0..1) -> 64 rows each
    const int wc     = wave & 1;    // wave col (0..1) -> 64 cols each

    const int rowBase = blockIdx.y * BM;
    const int colBase = blockIdx.x * BN;

    // staging: chunk c in [0,512): row = c>>2, kchunk = c&3 (16B per chunk)
    const int c0 = tid;
    const int c1 = tid + 256;
    const u16* Ag0 = A + (size_t)(rowBase + (c0 >> 2)) * K_DIM + (c0 & 3) * 8;
    const u16* Ag1 = A + (size_t)(rowBase + (c1 >> 2)) * K_DIM + (c1 & 3) * 8;
    const u16* Bg0 = B + (size_t)(colBase + (c0 >> 2)) * K_DIM + (c0 & 3) * 8;
    const u16* Bg1 = B + (size_t)(colBase + (c1 >> 2)) * K_DIM + (c1 & 3) * 8;
    u16* Al0 = &As[c0 * 8];
    u16* Al1 = &As[c1 * 8];
    u16* Bl0 = &Bs[c0 * 8];
    u16* Bl1 = &Bs[c1 * 8];

    f32x4 acc[4][4] = {};

    for (int k0 = 0; k0 < K_DIM; k0 += BK) {
        __syncthreads();                 // prior iter's LDS readers done
        load_lds16(Ag0 + k0, Al0);
        load_lds16(Ag1 + k0, Al1);
        load_lds16(Bg0 + k0, Bl0);
        load_lds16(Bg1 + k0, Bl1);
        __syncthreads();                 // compiler drains vmcnt before barrier

        bf16x8 af[4], bfv[4];
#pragma unroll
        for (int i = 0; i < 4; ++i)
            af[i] = *(const bf16x8*)&As[(wr * 64 + i * 16 + lane16) * BK + quad * 8];
#pragma unroll
        for (int j = 0; j < 4; ++j)
            bfv[j] = *(const bf16x8*)&Bs[(wc * 64 + j * 16 + lane16) * BK + quad * 8];
#pragma unroll
        for (int i = 0; i < 4; ++i)
#pragma unroll
            for (int j = 0; j < 4; ++j)
                acc[i][j] = __builtin_amdgcn_mfma_f32_16x16x32_bf16(
                    af[i], bfv[j], acc[i][j], 0, 0, 0);
    }

    // epilogue: C[row][col] = acc + bias[col]
    float bv[4];
#pragma unroll
    for (int j = 0; j < 4; ++j)
        bv[j] = bias[colBase + wc * 64 + j * 16 + lane16];
#pragma unroll
    for (int i = 0; i < 4; ++i) {
        int row0 = rowBase + wr * 64 + i * 16 + quad * 4;
#pragma unroll
        for (int r = 0; r < 4; ++r) {
            float* cp = C + (size_t)(row0 + r) * N_DIM + colBase + wc * 64 + lane16;
#pragma unroll
            for (int j = 0; j < 4; ++j)
                cp[j * 16] = acc[i][j][r] + bv[j];
        }
    }
}

extern "C" void kernel_launch(void* const* d_in, const int* in_sizes, int n_in,
                              void* d_out, int out_size, void* d_ws, size_t ws_size,
                              hipStream_t stream) {
    const float* x    = (const float*)d_in[0];
    const float* w    = (const float*)d_in[1];
    const float* bias = (const float*)d_in[2];
    float* out = (float*)d_out;

    u16* xb = (u16*)d_ws;                                      // 9,633,792 B
    u16* wb = (u16*)((char*)d_ws + (size_t)M_ROWS * K_DIM * 2); // +4,718,592 B

    hipLaunchKernelGGL(cast_x_kernel, dim3((M_ROWS * K_DIM / 8) / 256), dim3(256),
                       0, stream, x, xb);
    hipLaunchKernelGGL(expand_w_kernel, dim3((N_DIM * K_DIM / 8) / 256), dim3(256),
                       0, stream, w, wb);
    hipLaunchKernelGGL(gemm_bt, dim3(N_DIM / BN, M_ROWS / BM), dim3(256),
                       0, stream, xb, wb, bias, out);
}